// Round 6
// baseline (63.571 us; speedup 1.0000x reference)
//
#include <hip/hip_runtime.h>
#include <type_traits>

typedef __attribute__((ext_vector_type(4))) float f32x4;
typedef __attribute__((ext_vector_type(8))) short s16x8;

__device__ __forceinline__ unsigned short f2bf(float f) {
    unsigned int u = __builtin_bit_cast(unsigned int, f);
    u += 0x7fffu + ((u >> 16) & 1u);           // round-to-nearest-even
    return (unsigned short)(u >> 16);
}

// packed f32x2 -> bf16x2 (RNE), one HW instr
__device__ __forceinline__ unsigned cvtpk(float lo, float hi) {
    unsigned r;
    asm("v_cvt_pk_bf16_f32 %0, %1, %2" : "=v"(r) : "v"(lo), "v"(hi));
    return r;
}

__device__ __forceinline__ void gload_lds16(const void* g, void* l) {
    __builtin_amdgcn_global_load_lds(
        (const __attribute__((address_space(1))) void*)g,
        (__attribute__((address_space(3))) void*)l, 16, 0, 0);
}

// ---------------------------------------------------------------------------
// LDS tile section (bf16, 64 k-elems = 128 B per row):
//   byte(row, chunk) = row*128 + ((chunk ^ (row&7)) << 4)
// Staged via global_load_lds: linear LDS dest, pre-swizzled source chunk.
// ---------------------------------------------------------------------------
template<int ROWS>
__device__ __forceinline__ void stage_lds(const unsigned short* __restrict__ src,
                                          int ld, int row0, int k0, int maxRowExcl,
                                          char* lds, int wid, int lane) {
    const int subrow = lane >> 3;            // 0..7
    const int gchunk = (lane & 7) ^ subrow;  // inverse swizzle on source
    #pragma unroll
    for (int p = 0; p < (ROWS + 31) / 32; ++p) {
        const int r0 = (p * 4 + wid) * 8;    // 8 rows / wave-call
        int gr = row0 + r0 + subrow;
        if (gr >= maxRowExcl) gr = maxRowExcl - 1;
        const char* g = (const char*)(src + (size_t)gr * ld + k0) + gchunk * 16;
        gload_lds16(g, lds + r0 * 128);      // wave-uniform base + lane*16
    }
}

template<int MF, int NF>
__device__ __forceinline__ void mfma_all(const s16x8 (&af)[2][MF], const s16x8 (&bfr)[2][NF],
                                         f32x4 (&acc)[MF][NF]) {
    #pragma unroll
    for (int kk = 0; kk < 2; ++kk)
        #pragma unroll
        for (int mi = 0; mi < MF; ++mi)
            #pragma unroll
            for (int ni = 0; ni < NF; ++ni)
                acc[mi][ni] = __builtin_amdgcn_mfma_f32_16x16x32_bf16(
                    af[kk][mi], bfr[kk][ni], acc[mi][ni], 0, 0, 0);
}

// One BK=64 step from LDS (A) + LDS (B) — used by gemm1.
template<int MF, int NF>
__device__ __forceinline__ void compute_step(const char* As, const char* Bs,
                                             int arow_base, int brow_base,
                                             int lr, int lg, f32x4 (&acc)[MF][NF]) {
    s16x8 af[2][MF], bfr[2][NF];
    #pragma unroll
    for (int kk = 0; kk < 2; ++kk) {
        const int chunk = kk * 4 + lg;
        #pragma unroll
        for (int f = 0; f < MF; ++f) {
            const int row = arow_base + f * 16 + lr;
            af[kk][f] = *reinterpret_cast<const s16x8*>(As + row * 128 + ((chunk ^ (row & 7)) << 4));
        }
        #pragma unroll
        for (int f = 0; f < NF; ++f) {
            const int row = brow_base + f * 16 + lr;
            bfr[kk][f] = *reinterpret_cast<const s16x8*>(Bs + row * 128 + ((chunk ^ (row & 7)) << 4));
        }
    }
    mfma_all<MF, NF>(af, bfr, acc);
}

__device__ __forceinline__ int xcd_swizzle(int bid, int nwg) {
    const int q = nwg >> 3, r = nwg & 7;
    const int xcd = bid & 7, idx = bid >> 3;
    return (xcd < r ? xcd * (q + 1) : r * (q + 1) + (xcd - r) * q) + idx;
}

// ---------------------------------------------------------------------------
// K1: [0,512) W->Wt bf16 transpose; [512,768) x->xb bf16. 768 blocks.
// ---------------------------------------------------------------------------
__global__ __launch_bounds__(256) void prep_wx(const float* __restrict__ W,
                                               const float* __restrict__ x,
                                               unsigned short* __restrict__ Wt,
                                               unsigned short* __restrict__ xb) {
    const int bid = blockIdx.x, t = threadIdx.x;
    if (bid < 512) {
        __shared__ unsigned short tile[32][33];
        const int k0 = (bid & 31) * 32, n0 = (bid >> 5) * 32;
        const int c = t & 31, y = t >> 5;
        #pragma unroll
        for (int j = 0; j < 4; ++j)
            tile[y + j * 8][c] = f2bf(W[(size_t)(k0 + y + j * 8) * 512 + n0 + c]);
        __syncthreads();
        #pragma unroll
        for (int j = 0; j < 4; ++j)
            Wt[(size_t)(n0 + y + j * 8) * 1024 + k0 + c] = tile[c][y + j * 8];
    } else {
        const size_t base = (size_t)(bid - 512) * 2048 + (size_t)t * 8;
        const f32x4 v0 = *reinterpret_cast<const f32x4*>(x + base);
        const f32x4 v1 = *reinterpret_cast<const f32x4*>(x + base + 4);
        uint4 o;
        o.x = cvtpk(v0.x, v0.y);  o.y = cvtpk(v0.z, v0.w);
        o.z = cvtpk(v1.x, v1.y);  o.w = cvtpk(v1.z, v1.w);
        *reinterpret_cast<uint4*>(xb + base) = o;
    }
}

// ---------------------------------------------------------------------------
// K2: GEMM1  C1[512,512] = xb @ Wt^T (bf16 out). 32x64 tiles, dbuf, 128 blocks.
// ---------------------------------------------------------------------------
__global__ __launch_bounds__(256) void gemm1(const unsigned short* __restrict__ xb,
                                             const unsigned short* __restrict__ Wt,
                                             unsigned short* __restrict__ C1) {
    constexpr int MF = 1, NF = 2, BM = 32, BN = 64, M = 512, N = 512, K = 1024;
    constexpr int BUF = (BM + BN) * 128;
    __shared__ __align__(16) char lds[2 * BUF];

    const int bid = xcd_swizzle((int)blockIdx.x, 128);
    const int m0 = (bid & 15) * BM;        // nbM = 16
    const int n0 = (bid >> 4) * BN;

    const int tid = threadIdx.x, lane = tid & 63, wid = tid >> 6;
    const int wm = wid >> 1, wn = wid & 1;
    const int arow_base = wm * (16 * MF);
    const int brow_base = wn * (16 * NF);
    const int lr = lane & 15, lg = lane >> 4;

    f32x4 acc[MF][NF] = {};

    stage_lds<BM>(xb, K, m0, 0, M, lds, wid, lane);
    stage_lds<BN>(Wt, K, n0, 0, N, lds + BM * 128, wid, lane);
    __syncthreads();

    int cur = 0;
    for (int t = 0; t < K / 64; ++t) {
        char* curb = lds + cur * BUF;
        char* nxtb = lds + (cur ^ 1) * BUF;
        if (t < K / 64 - 1) {
            const int kn = (t + 1) * 64;
            stage_lds<BM>(xb, K, m0, kn, M, nxtb, wid, lane);
            stage_lds<BN>(Wt, K, n0, kn, N, nxtb + BM * 128, wid, lane);
        }
        compute_step<MF, NF>(curb, curb + BM * 128, arow_base, brow_base, lr, lg, acc);
        __syncthreads();
        cur ^= 1;
    }
    #pragma unroll
    for (int mi = 0; mi < MF; ++mi)
        #pragma unroll
        for (int ni = 0; ni < NF; ++ni) {
            const int gcol = n0 + brow_base + ni * 16 + lr;
            const int grow0 = m0 + arow_base + mi * 16 + lg * 4;
            #pragma unroll
            for (int r = 0; r < 4; ++r)
                C1[(size_t)(grow0 + r) * N + gcol] = f2bf(acc[mi][ni][r]);
        }
}

// ---------------------------------------------------------------------------
// K3: GEMM2  out[512,20000] = C1 @ E^T (f32), E read DIRECTLY as f32.
// Tile 128x160. A (C1 bf16): LDS half-K panels (128x256 = 64 KB), staged via
// global_load_lds; only 3 barriers per block. B (E f32): global -> reg ->
// v_cvt_pk_bf16_f32 -> MFMA, never touches LDS (frag = 16 rows x 32 B
// contiguous — fully coalesced; rows fully consumed over the 8 k-steps).
// Grid 504 = 8 XCDs x 63 (500 real): XCD-contiguous n-ranges, 4 m-blocks
// per E-panel adjacent. 2 blocks/CU.
// ---------------------------------------------------------------------------
__global__ __launch_bounds__(256, 2) void gemm2f(const unsigned short* __restrict__ C1,
                                                 const float* __restrict__ E,
                                                 float* __restrict__ out) {
    constexpr int MF = 4, NF = 5, BM = 128, BN = 160;
    constexpr int M = 512, N = 20000, K = 512;
    __shared__ __align__(16) char As[65536];        // 4 sections x [128 rows x 128 B]

    // bijective XCD decomposition of 500 over 8 XCDs (63,63,63,63,62,62,62,62)
    const int xcd = (int)blockIdx.x & 7, idx = (int)blockIdx.x >> 3;
    if (xcd >= 4 && idx >= 62) return;
    const int nb = (xcd < 4 ? xcd * 63 : 252 + (xcd - 4) * 62) + idx;
    const int m0 = (nb & 3) * BM;                   // 4 consecutive nb share E panel
    const int n0 = (nb >> 2) * BN;

    const int tid = threadIdx.x, lane = tid & 63, wid = tid >> 6;
    const int wm = wid >> 1, wn = wid & 1;
    const int arow_base = wm * (16 * MF);           // 0 / 64
    const int brow_base = wn * (16 * NF);           // 0 / 80
    const int lr = lane & 15, lg = lane >> 4;

    f32x4 acc[MF][NF] = {};

    // B row base pointers (5 rows this lane touches)
    const float* brow[NF];
    #pragma unroll
    for (int f = 0; f < NF; ++f)
        brow[f] = E + (size_t)(n0 + brow_base + f * 16 + lr) * 512;

    // stage A half 0: k in [0,256) -> sections 0..3
    #pragma unroll
    for (int s = 0; s < 4; ++s)
        stage_lds<BM>(C1, K, m0, s * 64, M, As + s * 16384, wid, lane);
    __syncthreads();

    #pragma unroll 1
    for (int h = 0; h < 2; ++h) {
        #pragma unroll 1
        for (int t = 0; t < 4; ++t) {
            const int gk = (h * 4 + t) * 64;        // global k base of this step
            const char* sec = As + t * 16384;
            s16x8 af[2][MF], bfr[2][NF];
            #pragma unroll
            for (int kk = 0; kk < 2; ++kk) {
                const int c = kk * 4 + lg;
                #pragma unroll
                for (int f = 0; f < NF; ++f) {
                    const float* p = brow[f] + gk + c * 8;
                    const f32x4 v0 = *reinterpret_cast<const f32x4*>(p);
                    const f32x4 v1 = *reinterpret_cast<const f32x4*>(p + 4);
                    uint4 u;
                    u.x = cvtpk(v0.x, v0.y);  u.y = cvtpk(v0.z, v0.w);
                    u.z = cvtpk(v1.x, v1.y);  u.w = cvtpk(v1.z, v1.w);
                    bfr[kk][f] = __builtin_bit_cast(s16x8, u);
                }
                #pragma unroll
                for (int f = 0; f < MF; ++f) {
                    const int row = arow_base + f * 16 + lr;
                    af[kk][f] = *reinterpret_cast<const s16x8*>(sec + row * 128 + ((c ^ (row & 7)) << 4));
                }
            }
            mfma_all<MF, NF>(af, bfr, acc);
        }
        if (h == 0) {
            __syncthreads();                        // all reads of half 0 done
            #pragma unroll
            for (int s = 0; s < 4; ++s)             // stage half 1: k in [256,512)
                stage_lds<BM>(C1, K, m0, 256 + s * 64, M, As + s * 16384, wid, lane);
            __syncthreads();
        }
    }

    // epilogue: C/D layout col = lane&15, row = (lane>>4)*4 + reg   [m89]
    #pragma unroll
    for (int mi = 0; mi < MF; ++mi)
        #pragma unroll
        for (int ni = 0; ni < NF; ++ni) {
            const int gcol = n0 + brow_base + ni * 16 + lr;
            const int grow0 = m0 + arow_base + mi * 16 + lg * 4;
            #pragma unroll
            for (int r = 0; r < 4; ++r)
                __builtin_nontemporal_store(acc[mi][ni][r],
                    &out[(size_t)(grow0 + r) * N + gcol]);
        }
}

// ---------------------------------------------------------------------------

extern "C" void kernel_launch(void* const* d_in, const int* in_sizes, int n_in,
                              void* d_out, int out_size, void* d_ws, size_t ws_size,
                              hipStream_t stream) {
    const float* x = (const float*)d_in[0];     // [512,1024]
    const float* E = (const float*)d_in[1];     // [20000,512]
    const float* W = (const float*)d_in[2];     // [1024,512]
    float* out = (float*)d_out;                 // [512,20000]

    char* ws = (char*)d_ws;
    unsigned short* C1 = (unsigned short*)ws;                     // 512 KiB
    unsigned short* xb = (unsigned short*)(ws + 524288);          // 1 MiB
    unsigned short* Wt = (unsigned short*)(ws + 1572864);         // 1 MiB

    // K1: Wt + xb (bf16 prep), 768 blocks, ~1.5 us
    prep_wx<<<768, 256, 0, stream>>>(W, x, Wt, xb);

    // K2: C1 = xb @ Wt^T, 128 blocks
    gemm1<<<128, 256, 0, stream>>>(xb, Wt, C1);

    // K3: out = C1 @ E^T, E streamed as f32, 504 blocks (500 real)
    gemm2f<<<504, 256, 0, stream>>>(C1, E, out);
}

// Round 7
// 36.604 us; speedup vs baseline: 1.7367x; 1.7367x over previous
//
#include <hip/hip_runtime.h>
#include <type_traits>

typedef __attribute__((ext_vector_type(4))) float f32x4;
typedef __attribute__((ext_vector_type(8))) short s16x8;

__device__ __forceinline__ unsigned short f2bf(float f) {
    unsigned int u = __builtin_bit_cast(unsigned int, f);
    u += 0x7fffu + ((u >> 16) & 1u);           // round-to-nearest-even
    return (unsigned short)(u >> 16);
}

// packed f32x2 -> bf16x2 (RNE), one HW instr
__device__ __forceinline__ unsigned cvtpk(float lo, float hi) {
    unsigned r;
    asm("v_cvt_pk_bf16_f32 %0, %1, %2" : "=v"(r) : "v"(lo), "v"(hi));
    return r;
}

__device__ __forceinline__ void gload_lds16(const void* g, void* l) {
    __builtin_amdgcn_global_load_lds(
        (const __attribute__((address_space(1))) void*)g,
        (__attribute__((address_space(3))) void*)l, 16, 0, 0);
}

// ---------------------------------------------------------------------------
// LDS tile section (bf16, 64 k-elems = 128 B per row):
//   byte(row, chunk) = row*128 + ((chunk ^ (row&7)) << 4)
// ---------------------------------------------------------------------------
template<int ROWS>
__device__ __forceinline__ void stage_lds(const unsigned short* __restrict__ src,
                                          int ld, int row0, int k0, int maxRowExcl,
                                          char* lds, int wid, int lane) {
    const int subrow = lane >> 3;            // 0..7
    const int gchunk = (lane & 7) ^ subrow;  // inverse swizzle on source
    #pragma unroll
    for (int p = 0; p < (ROWS + 31) / 32; ++p) {
        const int r0 = (p * 4 + wid) * 8;    // 8 rows / wave-call
        int gr = row0 + r0 + subrow;
        if (gr >= maxRowExcl) gr = maxRowExcl - 1;
        const char* g = (const char*)(src + (size_t)gr * ld + k0) + gchunk * 16;
        gload_lds16(g, lds + r0 * 128);      // wave-uniform base + lane*16
    }
}

template<int MF, int NF>
__device__ __forceinline__ void mfma_all(const s16x8 (&af)[2][MF], const s16x8 (&bfr)[2][NF],
                                         f32x4 (&acc)[MF][NF]) {
    #pragma unroll
    for (int kk = 0; kk < 2; ++kk)
        #pragma unroll
        for (int mi = 0; mi < MF; ++mi)
            #pragma unroll
            for (int ni = 0; ni < NF; ++ni)
                acc[mi][ni] = __builtin_amdgcn_mfma_f32_16x16x32_bf16(
                    af[kk][mi], bfr[kk][ni], acc[mi][ni], 0, 0, 0);
}

// One BK=64 step from LDS (A) + LDS (B).
template<int MF, int NF>
__device__ __forceinline__ void compute_step(const char* As, const char* Bs,
                                             int arow_base, int brow_base,
                                             int lr, int lg, f32x4 (&acc)[MF][NF]) {
    s16x8 af[2][MF], bfr[2][NF];
    #pragma unroll
    for (int kk = 0; kk < 2; ++kk) {
        const int chunk = kk * 4 + lg;
        #pragma unroll
        for (int f = 0; f < MF; ++f) {
            const int row = arow_base + f * 16 + lr;
            af[kk][f] = *reinterpret_cast<const s16x8*>(As + row * 128 + ((chunk ^ (row & 7)) << 4));
        }
        #pragma unroll
        for (int f = 0; f < NF; ++f) {
            const int row = brow_base + f * 16 + lr;
            bfr[kk][f] = *reinterpret_cast<const s16x8*>(Bs + row * 128 + ((chunk ^ (row & 7)) << 4));
        }
    }
    mfma_all<MF, NF>(af, bfr, acc);
}

__device__ __forceinline__ int xcd_swizzle(int bid, int nwg) {
    const int q = nwg >> 3, r = nwg & 7;
    const int xcd = bid & 7, idx = bid >> 3;
    return (xcd < r ? xcd * (q + 1) : r * (q + 1) + (xcd - r) * q) + idx;
}

// ---------------------------------------------------------------------------
// K1: [0,512) W->Wt bf16 transpose; [512,768) x->xb bf16. 768 blocks.
// ---------------------------------------------------------------------------
__global__ __launch_bounds__(256) void prep_wx(const float* __restrict__ W,
                                               const float* __restrict__ x,
                                               unsigned short* __restrict__ Wt,
                                               unsigned short* __restrict__ xb) {
    const int bid = blockIdx.x, t = threadIdx.x;
    if (bid < 512) {
        __shared__ unsigned short tile[32][33];
        const int k0 = (bid & 31) * 32, n0 = (bid >> 5) * 32;
        const int c = t & 31, y = t >> 5;
        #pragma unroll
        for (int j = 0; j < 4; ++j)
            tile[y + j * 8][c] = f2bf(W[(size_t)(k0 + y + j * 8) * 512 + n0 + c]);
        __syncthreads();
        #pragma unroll
        for (int j = 0; j < 4; ++j)
            Wt[(size_t)(n0 + y + j * 8) * 1024 + k0 + c] = tile[c][y + j * 8];
    } else {
        const size_t base = (size_t)(bid - 512) * 2048 + (size_t)t * 8;
        const f32x4 v0 = *reinterpret_cast<const f32x4*>(x + base);
        const f32x4 v1 = *reinterpret_cast<const f32x4*>(x + base + 4);
        uint4 o;
        o.x = cvtpk(v0.x, v0.y);  o.y = cvtpk(v0.z, v0.w);
        o.z = cvtpk(v1.x, v1.y);  o.w = cvtpk(v1.z, v1.w);
        *reinterpret_cast<uint4*>(xb + base) = o;
    }
}

// ---------------------------------------------------------------------------
// K2: GEMM1  C1[512,512] = xb @ Wt^T (bf16 out). 32x64 tiles, dbuf, 128 blocks.
// ---------------------------------------------------------------------------
__global__ __launch_bounds__(256) void gemm1(const unsigned short* __restrict__ xb,
                                             const unsigned short* __restrict__ Wt,
                                             unsigned short* __restrict__ C1) {
    constexpr int MF = 1, NF = 2, BM = 32, BN = 64, M = 512, N = 512, K = 1024;
    constexpr int BUF = (BM + BN) * 128;
    __shared__ __align__(16) char lds[2 * BUF];

    const int bid = xcd_swizzle((int)blockIdx.x, 128);
    const int m0 = (bid & 15) * BM;        // nbM = 16
    const int n0 = (bid >> 4) * BN;

    const int tid = threadIdx.x, lane = tid & 63, wid = tid >> 6;
    const int wm = wid >> 1, wn = wid & 1;
    const int arow_base = wm * (16 * MF);
    const int brow_base = wn * (16 * NF);
    const int lr = lane & 15, lg = lane >> 4;

    f32x4 acc[MF][NF] = {};

    stage_lds<BM>(xb, K, m0, 0, M, lds, wid, lane);
    stage_lds<BN>(Wt, K, n0, 0, N, lds + BM * 128, wid, lane);
    __syncthreads();

    int cur = 0;
    for (int t = 0; t < K / 64; ++t) {
        char* curb = lds + cur * BUF;
        char* nxtb = lds + (cur ^ 1) * BUF;
        if (t < K / 64 - 1) {
            const int kn = (t + 1) * 64;
            stage_lds<BM>(xb, K, m0, kn, M, nxtb, wid, lane);
            stage_lds<BN>(Wt, K, n0, kn, N, nxtb + BM * 128, wid, lane);
        }
        compute_step<MF, NF>(curb, curb + BM * 128, arow_base, brow_base, lr, lg, acc);
        __syncthreads();
        cur ^= 1;
    }
    #pragma unroll
    for (int mi = 0; mi < MF; ++mi)
        #pragma unroll
        for (int ni = 0; ni < NF; ++ni) {
            const int gcol = n0 + brow_base + ni * 16 + lr;
            const int grow0 = m0 + arow_base + mi * 16 + lg * 4;
            #pragma unroll
            for (int r = 0; r < 4; ++r)
                C1[(size_t)(grow0 + r) * N + gcol] = f2bf(acc[mi][ni][r]);
        }
}

// ---------------------------------------------------------------------------
// K3: GEMM2  out[512,20000] = C1 @ E^T (f32). Tile 128x160, BK=64, 8 K-steps.
// A (C1 bf16): global_load_lds, 4/wave/step.  B (E f32): coalesced global ->
// regs (10 dwordx4/thread), cvt_pk -> ds_write into the freed buffer (T14).
// ONE raw s_barrier per K-step; counted vmcnt — B loads stay in flight across
// the barrier, only A's gload_lds is drained (vmcnt(10)).
// Wait ledger per iter t: outstanding on entry = A(t)=4.
//   +B(t+1)=10 -> 14; vmcnt(10) drains A(t); lgkm(0) publishes my B(t) writes;
//   s_barrier  => buf[t&1] complete (all waves), buf[(t+1)&1] free;
//   +A(t+1)=4 into nxt; ds_read frags + MFMA on cur;
//   [compiler vmcnt] cvt+ds_write B(t+1) -> nxt.  Invariant restored.
// Grid 504 = 8 XCDs x 63 (500 real; 20000 = 125*160, no N edge); 4 m-blocks
// sharing one E panel are XCD-adjacent. LDS 72 KiB -> 2 blocks/CU.
// ---------------------------------------------------------------------------
__global__ __launch_bounds__(256, 2) void gemm2fused(const unsigned short* __restrict__ C1,
                                                     const float* __restrict__ E,
                                                     float* __restrict__ out) {
    constexpr int MF = 4, NF = 5, BM = 128, BN = 160;
    constexpr int M = 512, N = 20000, K = 512, NSTEP = K / 64;
    constexpr int ABUF = BM * 128;                 // 16384
    constexpr int BUF = (BM + BN) * 128;           // 36864
    __shared__ __align__(16) char lds[2 * BUF];    // 72 KiB

    // bijective XCD decomposition of 500 over 8 XCDs (63,63,63,63,62,62,62,62)
    const int xcd = (int)blockIdx.x & 7, idx = (int)blockIdx.x >> 3;
    if (xcd >= 4 && idx >= 62) return;
    const int nb = (xcd < 4 ? xcd * 63 : 252 + (xcd - 4) * 62) + idx;
    const int m0 = (nb & 3) * BM;                  // 4 consecutive nb share E panel
    const int n0 = (nb >> 2) * BN;

    const int tid = threadIdx.x, lane = tid & 63, wid = tid >> 6;
    const int wm = wid >> 1, wn = wid & 1;
    const int arow_base = wm * (16 * MF);          // 0 / 64
    const int brow_base = wn * (16 * NF);          // 0 / 80
    const int lr = lane & 15, lg = lane >> 4;

    // B staging assignment: 16 threads per row, thread covers rows p*16+r_in
    const int r_in = tid >> 4, c4 = tid & 15;

    f32x4 acc[MF][NF] = {};
    f32x4 breg[10];

    auto loadB = [&](int k0) {
        #pragma unroll
        for (int p = 0; p < 10; ++p)
            breg[p] = *reinterpret_cast<const f32x4*>(
                E + (size_t)(n0 + p * 16 + r_in) * 512 + k0 + c4 * 4);
    };
    auto writeB = [&](char* Bs) {
        #pragma unroll
        for (int p = 0; p < 10; ++p) {
            const int row = p * 16 + r_in;
            const unsigned lo = cvtpk(breg[p].x, breg[p].y);
            const unsigned hi = cvtpk(breg[p].z, breg[p].w);
            const int byte = row * 128 + ((((c4 >> 1)) ^ (row & 7)) << 4) + (c4 & 1) * 8;
            *reinterpret_cast<uint2*>(Bs + byte) = make_uint2(lo, hi);
        }
    };

    // prologue: tile 0 — B regs + A gload; write B0; leave A0 in flight
    loadB(0);                                       // vm: B0=10
    stage_lds<BM>(C1, K, m0, 0, M, lds, wid, lane); // vm: +A0=4 -> 14
    writeB(lds + ABUF);                             // compiler waits breg (vmcnt 4)

    #pragma unroll 1
    for (int t = 0; t < NSTEP; ++t) {
        char* cur = lds + (t & 1) * BUF;
        char* nxt = lds + ((t + 1) & 1) * BUF;
        if (t < NSTEP - 1) {
            loadB((t + 1) * 64);                    // B(t+1) regs, in flight
            asm volatile("s_waitcnt vmcnt(10)" ::: "memory");   // A(t) landed
        } else {
            asm volatile("s_waitcnt vmcnt(0)" ::: "memory");
        }
        asm volatile("s_waitcnt lgkmcnt(0)" ::: "memory");      // publish my ds_writes
        __builtin_amdgcn_s_barrier();               // tile t complete; nxt free
        if (t < NSTEP - 1)
            stage_lds<BM>(C1, K, m0, (t + 1) * 64, M, nxt, wid, lane);  // A(t+1)
        compute_step<MF, NF>(cur, cur + ABUF, arow_base, brow_base, lr, lg, acc);
        if (t < NSTEP - 1)
            writeB(nxt + ABUF);                     // cvt+write B(t+1) (late, T14)
    }

    // epilogue: plain stores (nontemporal caused 40->55 MB write amplification)
    #pragma unroll
    for (int mi = 0; mi < MF; ++mi)
        #pragma unroll
        for (int ni = 0; ni < NF; ++ni) {
            const int gcol = n0 + brow_base + ni * 16 + lr;
            const int grow0 = m0 + arow_base + mi * 16 + lg * 4;
            #pragma unroll
            for (int r = 0; r < 4; ++r)
                out[(size_t)(grow0 + r) * N + gcol] = acc[mi][ni][r];
        }
}

// ---------------------------------------------------------------------------

extern "C" void kernel_launch(void* const* d_in, const int* in_sizes, int n_in,
                              void* d_out, int out_size, void* d_ws, size_t ws_size,
                              hipStream_t stream) {
    const float* x = (const float*)d_in[0];     // [512,1024]
    const float* E = (const float*)d_in[1];     // [20000,512]
    const float* W = (const float*)d_in[2];     // [1024,512]
    float* out = (float*)d_out;                 // [512,20000]

    char* ws = (char*)d_ws;
    unsigned short* C1 = (unsigned short*)ws;                     // 512 KiB
    unsigned short* xb = (unsigned short*)(ws + 524288);          // 1 MiB
    unsigned short* Wt = (unsigned short*)(ws + 1572864);         // 1 MiB

    // K1: Wt + xb (bf16 prep), 768 blocks
    prep_wx<<<768, 256, 0, stream>>>(W, x, Wt, xb);

    // K2: C1 = xb @ Wt^T, 128 blocks
    gemm1<<<128, 256, 0, stream>>>(xb, Wt, C1);

    // K3: out = C1 @ E^T, E streamed f32 once, 504 blocks (500 real)
    gemm2fused<<<504, 256, 0, stream>>>(C1, E, out);
}